// Round 19
// baseline (1195.948 us; speedup 1.0000x reference)
//
#include <hip/hip_runtime.h>
#include <hip/hip_bf16.h>

typedef _Float16 half8 __attribute__((ext_vector_type(8)));
typedef _Float16 half4v __attribute__((ext_vector_type(4)));
typedef float floatx4 __attribute__((ext_vector_type(4)));

// ---------------------------------------------------------------------------
__device__ inline void gload_lds16(const void* g, void* l) {
  __builtin_amdgcn_global_load_lds(
      (const __attribute__((address_space(1))) unsigned int*)g,
      (__attribute__((address_space(3))) unsigned int*)l, 16, 0, 0);
}
__device__ inline unsigned lds_off(const void* p) {
  return (unsigned)(uintptr_t)(const __attribute__((address_space(3))) char*)p;
}
__device__ inline half8 ds_read128(unsigned off) {
  half8 r;
  asm volatile("ds_read_b128 %0, %1" : "=v"(r) : "v"(off));
  return r;
}
#define BARB()   __builtin_amdgcn_s_barrier()
#define WAITL0() asm volatile("s_waitcnt lgkmcnt(0)")
#define WAITV(n) asm volatile("s_waitcnt vmcnt(" #n ")")
#define SCHED0() __builtin_amdgcn_sched_barrier(0)

// Panel-chunked n-fast XCD swizzle (round-8).  Identity if gridDim.y%8 != 0.
__device__ inline void xcd_chunk_decode(int* mb, int* nk) {
  if (gridDim.y & 7) { *mb = blockIdx.x; *nk = blockIdx.y; return; }
  const int gx = gridDim.x;
  const int nb = gx * gridDim.y;
  const int b = blockIdx.x + gx * blockIdx.y;
  const int s = (b & 7) * (nb >> 3) + (b >> 3);  // bijective
  const int PW = gx * 8;
  const int p = s / PW, r = s % PW;
  *mb = r >> 3;
  *nk = p * 8 + (r & 7);
}

// ---------------------------------------------------------------------------
__global__ __launch_bounds__(256) void gates_kernel(
    const float* __restrict__ x, const float* __restrict__ gw,
    const float* __restrict__ gb, float* __restrict__ gates) {
  const int lane = threadIdx.x & 63, wid = threadIdx.x >> 6;
  const int n = blockIdx.x * 4 + wid;
  const float* xr = x + (size_t)n * 1024;
  float xv[16];
#pragma unroll
  for (int i = 0; i < 16; ++i) xv[i] = xr[lane + i * 64];
  float logit[8];
#pragma unroll
  for (int e = 0; e < 8; ++e) {
    const float* wr = gw + (size_t)e * 1024;
    float p = 0.f;
#pragma unroll
    for (int i = 0; i < 16; ++i) p += xv[i] * wr[lane + i * 64];
#pragma unroll
    for (int off = 32; off > 0; off >>= 1) p += __shfl_xor(p, off);
    logit[e] = p + gb[e];
  }
  float mx = logit[0];
#pragma unroll
  for (int e = 1; e < 8; ++e) mx = fmaxf(mx, logit[e]);
  float s = 0.f;
#pragma unroll
  for (int e = 0; e < 8; ++e) { logit[e] = expf(logit[e] - mx); s += logit[e]; }
  if (lane < 8) gates[(size_t)n * 8 + lane] = logit[lane] / s;
}

// ---------------------------------------------------------------------------
// out = p1 + p2 + sum_e gates*b2  (2 partials; fallback tiers)
__global__ __launch_bounds__(256) void combine_kernel(
    const float* __restrict__ gates, const float* __restrict__ b2,
    const _Float16* __restrict__ p1, const _Float16* __restrict__ p2,
    float* __restrict__ out) {
  const int i = blockIdx.x * 256 + threadIdx.x;
  const int n = i >> 7;
  const int d0 = (i & 127) << 3;
  const half8 a = *(const half8*)(p1 + ((size_t)n * 1024 + d0));
  const half8 b = *(const half8*)(p2 + ((size_t)n * 1024 + d0));
  float s[8];
#pragma unroll
  for (int j = 0; j < 8; ++j) s[j] = (float)a[j] + (float)b[j];
  const float* g = gates + (size_t)n * 8;
#pragma unroll
  for (int e = 0; e < 8; ++e) {
    const float ge = g[e];
    const float4* bb = (const float4*)(b2 + (size_t)e * 1024 + d0);
    const float4 b0 = bb[0], b1v = bb[1];
    s[0] += ge * b0.x; s[1] += ge * b0.y; s[2] += ge * b0.z; s[3] += ge * b0.w;
    s[4] += ge * b1v.x; s[5] += ge * b1v.y; s[6] += ge * b1v.z; s[7] += ge * b1v.w;
  }
  float4* o = (float4*)(out + (size_t)n * 1024 + d0);
  o[0] = make_float4(s[0], s[1], s[2], s[3]);
  o[1] = make_float4(s[4], s[5], s[6], s[7]);
}

// ---------------------------------------------------------------------------
// out = sum_{i<8} pAll[i] + sum_e gates*b2  (8 fp16 partials, pure store)
__global__ __launch_bounds__(256) void combine8_kernel(
    const float* __restrict__ gates, const float* __restrict__ b2,
    const _Float16* __restrict__ pAll, float* __restrict__ out) {
  const int i = blockIdx.x * 256 + threadIdx.x;  // 8 elems/thread
  const int n = i >> 7;
  const int d0 = (i & 127) << 3;
  const size_t off = (size_t)n * 1024 + d0;
  const size_t stride = (size_t)8192 * 1024;  // N*D
  float s[8] = {0, 0, 0, 0, 0, 0, 0, 0};
#pragma unroll
  for (int pi = 0; pi < 8; ++pi) {
    const half8 a = *(const half8*)(pAll + pi * stride + off);
#pragma unroll
    for (int j = 0; j < 8; ++j) s[j] += (float)a[j];
  }
  const float* g = gates + (size_t)n * 8;
#pragma unroll
  for (int e = 0; e < 8; ++e) {
    const float ge = g[e];
    const float4* bb = (const float4*)(b2 + (size_t)e * 1024 + d0);
    const float4 b0 = bb[0], b1v = bb[1];
    s[0] += ge * b0.x; s[1] += ge * b0.y; s[2] += ge * b0.z; s[3] += ge * b0.w;
    s[4] += ge * b1v.x; s[5] += ge * b1v.y; s[6] += ge * b1v.z; s[7] += ge * b1v.w;
  }
  float4* o = (float4*)(out + (size_t)n * 1024 + d0);
  o[0] = make_float4(s[0], s[1], s[2], s[3]);
  o[1] = make_float4(s[4], s[5], s[6], s[7]);
}

// ---------------------------------------------------------------------------
__global__ __launch_bounds__(256) void cvt_f32_f16_kernel(
    const float* __restrict__ in, _Float16* __restrict__ out, int n8) {
  const int i = blockIdx.x * 256 + threadIdx.x;
  if (i >= n8) return;
  const float4* p = (const float4*)(in + (size_t)i * 8);
  float4 a = p[0], b = p[1];
  half8 h;
  h[0] = (_Float16)a.x; h[1] = (_Float16)a.y; h[2] = (_Float16)a.z; h[3] = (_Float16)a.w;
  h[4] = (_Float16)b.x; h[5] = (_Float16)b.y; h[6] = (_Float16)b.z; h[7] = (_Float16)b.w;
  *(half8*)(out + (size_t)i * 8) = h;
}

// ---------------------------------------------------------------------------
// Vectorized transpose+cvt (verified r12/r14): out[z][c][r] = (fp16)
// in[z][r][c].  GRID CONTRACT: dim3(C/32, R/32, z).
__global__ __launch_bounds__(256) void transpose_cvt_kernel(
    const float* __restrict__ in, _Float16* __restrict__ out, int R, int C) {
  __shared__ _Float16 tile[32][36];
  const float* src = in + (size_t)blockIdx.z * R * C;
  _Float16* dst = out + (size_t)blockIdx.z * R * C;
  const int c0 = blockIdx.x << 5, r0 = blockIdx.y << 5;
  const int lr = threadIdx.x >> 3, lc = (threadIdx.x & 7) << 2;
  const float4 v = *(const float4*)&src[(size_t)(r0 + lr) * C + c0 + lc];
  half4v h;
  h[0] = (_Float16)v.x; h[1] = (_Float16)v.y;
  h[2] = (_Float16)v.z; h[3] = (_Float16)v.w;
  *(half4v*)&tile[lr][lc] = h;
  __syncthreads();
  const int oc = threadIdx.x >> 3, orr = (threadIdx.x & 7) << 2;
  half4v o;
#pragma unroll
  for (int i = 0; i < 4; ++i) o[i] = tile[orr + i][oc];
  *(half4v*)&dst[(size_t)(c0 + oc) * R + r0 + orr] = o;
}

// ---------------------------------------------------------------------------
// 256x256-tile, BK=64, 8-phase pipelined f16 MFMA GEMM — EXACT round-9
// staging schedule (best measured).
// EPI 0: Hout[gr*Nout + gc] = gate[gr][ebase + (n0>>12)] * relu(acc+bias[gc]).
// EPI 1: q = nk>>2 in {0,1}: K-window kb = q*kOff; operands {A,Bt} for q=0,
//   {A2,B2} for q=1 (dual-pointer K-halves); dest q? p2 : p1 (fp16,
//   exclusive owner); beta ? RMW : store.  Lower tiers pass A2=A, B2=Bt.
template <int EPI>
__global__ __launch_bounds__(512, 2) void gemm256_kernel(
    const _Float16* __restrict__ A, const _Float16* __restrict__ Bt,
    const _Float16* __restrict__ A2, const _Float16* __restrict__ B2,
    const float* __restrict__ bias, const float* __restrict__ gates,
    int ebase, _Float16* __restrict__ Hout, _Float16* __restrict__ p1,
    _Float16* __restrict__ p2, int beta, int kOff, int lda, int ldb,
    int kLen, int Nout) {
  __shared__ _Float16 smem[2][4][8192];  // [buf][A0,A1,B0,B1][16KB]
  const int tid = threadIdx.x, lane = tid & 63, wid = tid >> 6;
  const int wm = wid >> 2, wn = wid & 3;

  int mb, nk;
  xcd_chunk_decode(&mb, &nk);
  const int m0 = mb * 256;
  int n0, kb = 0, q = 0;
  if (EPI == 1) { q = nk >> 2; n0 = (nk & 3) * 256; kb = q * kOff; }
  else          { n0 = nk * 256; }
  const int eg = (EPI == 0) ? ebase + (n0 >> 12) : 0;
  const int NT = kLen >> 6;

  const _Float16* Ap = (EPI == 1 && q) ? A2 : A;
  const _Float16* Bp = (EPI == 1 && q) ? B2 : Bt;

  floatx4 acc[8][4] = {};

  auto stage_half = [&](int h) {
    if (h >= 4 * NT) return;
    const int th = h >> 2, j = h & 3, bf = th & 1;
    const int k0 = kb + th * 64;
    const char* gb; int ld, rorig;
    if (j < 2) { gb = (const char*)Ap; ld = lda; rorig = m0 + j * 128; }
    else       { gb = (const char*)Bp; ld = ldb; rorig = n0 + (j - 2) * 128; }
    _Float16* lb = &smem[bf][j][0];
#pragma unroll
    for (int i = 0; i < 2; ++i) {
      const int row = (wid * 2 + i) * 8 + (lane >> 3);
      const int gkb = ((lane & 7) * 16) ^ ((row & 7) << 4);  // inverse swizzle
      gload_lds16(gb + ((size_t)(rorig + row) * ld + k0) * 2 + gkb,
                  lb + (wid * 2 + i) * 512 + lane * 8);
    }
  };

  const unsigned smem0 = lds_off(&smem[0][0][0]);
  auto ldA = [&](int bf, int mf, int ks) -> half8 {
    const int row = mf * 16 + (lane & 15);
    const int col = (ks * 64 + ((lane >> 4) << 4)) ^ ((row & 7) << 4);
    return ds_read128(smem0 + (bf * 4 + wm) * 16384 + row * 128 + col);
  };
  auto ldB = [&](int bf, int nf, int ks) -> half8 {
    const int c = wn * 64 + nf * 16 + (lane & 15);
    const int r = c & 127;
    const int col = (ks * 64 + ((lane >> 4) << 4)) ^ ((r & 7) << 4);
    return ds_read128(smem0 + (bf * 4 + 2 + (c >> 7)) * 16384 + r * 128 + col);
  };

  stage_half(0); stage_half(1); stage_half(2); stage_half(3);
  stage_half(4 * 1 + 2); stage_half(4 * 1 + 3);
  WAITV(4); SCHED0();
  BARB();

#pragma unroll 1
  for (int t = 0; t < NT; ++t) {
    const int bf = t & 1;
    half8 a[4][2], bh[2][2], bl[2][2];
    // ---- P1
#pragma unroll
    for (int ks = 0; ks < 2; ++ks) {
#pragma unroll
      for (int m = 0; m < 4; ++m) a[m][ks] = ldA(bf, m, ks);
#pragma unroll
      for (int n = 0; n < 2; ++n) bh[n][ks] = ldB(bf, 2 + n, ks);
    }
    stage_half(4 * (t + 1) + 0);
    BARB(); WAITL0(); SCHED0();
    __builtin_amdgcn_s_setprio(1);
#pragma unroll
    for (int m = 0; m < 4; ++m)
#pragma unroll
      for (int n = 0; n < 2; ++n)
#pragma unroll
        for (int ks = 0; ks < 2; ++ks)
          acc[m][2 + n] = __builtin_amdgcn_mfma_f32_16x16x32_f16(
              a[m][ks], bh[n][ks], acc[m][2 + n], 0, 0, 0);
    __builtin_amdgcn_s_setprio(0);
    BARB();
    // ---- P2
#pragma unroll
    for (int ks = 0; ks < 2; ++ks)
#pragma unroll
      for (int n = 0; n < 2; ++n) bl[n][ks] = ldB(bf, n, ks);
    stage_half(4 * (t + 1) + 1);
    BARB(); WAITL0(); SCHED0();
    __builtin_amdgcn_s_setprio(1);
#pragma unroll
    for (int m = 0; m < 4; ++m)
#pragma unroll
      for (int n = 0; n < 2; ++n)
#pragma unroll
        for (int ks = 0; ks < 2; ++ks)
          acc[m][n] = __builtin_amdgcn_mfma_f32_16x16x32_f16(
              a[m][ks], bl[n][ks], acc[m][n], 0, 0, 0);
    __builtin_amdgcn_s_setprio(0);
    BARB();
    // ---- P3
#pragma unroll
    for (int ks = 0; ks < 2; ++ks)
#pragma unroll
      for (int m = 0; m < 4; ++m) a[m][ks] = ldA(bf, 4 + m, ks);
    stage_half(4 * (t + 2) + 2);
    BARB(); WAITL0(); SCHED0();
    __builtin_amdgcn_s_setprio(1);
#pragma unroll
    for (int m = 0; m < 4; ++m)
#pragma unroll
      for (int n = 0; n < 2; ++n)
#pragma unroll
        for (int ks = 0; ks < 2; ++ks)
          acc[4 + m][2 + n] = __builtin_amdgcn_mfma_f32_16x16x32_f16(
              a[m][ks], bh[n][ks], acc[4 + m][2 + n], 0, 0, 0);
    __builtin_amdgcn_s_setprio(0);
    BARB();
    // ---- P4
    stage_half(4 * (t + 2) + 3);
    BARB();
    __builtin_amdgcn_s_setprio(1);
#pragma unroll
    for (int m = 0; m < 4; ++m)
#pragma unroll
      for (int n = 0; n < 2; ++n)
#pragma unroll
        for (int ks = 0; ks < 2; ++ks)
          acc[4 + m][n] = __builtin_amdgcn_mfma_f32_16x16x32_f16(
              a[m][ks], bl[n][ks], acc[4 + m][n], 0, 0, 0);
    __builtin_amdgcn_s_setprio(0);
    if (t + 2 < NT) { WAITV(4); } else { WAITV(0); }
    SCHED0();
    BARB();
  }

  // epilogue: D-frag col = lane&15, row = (lane>>4)*4 + r
#pragma unroll
  for (int mf = 0; mf < 8; ++mf) {
    const int gr0 = m0 + wm * 128 + mf * 16 + ((lane >> 4) << 2);
#pragma unroll
    for (int r = 0; r < 4; ++r) {
      const int gr = gr0 + r;
      float g = 0.f;
      if (EPI == 0) g = gates[(size_t)gr * 8 + eg];
#pragma unroll
      for (int nf = 0; nf < 4; ++nf) {
        const int gc = n0 + wn * 64 + nf * 16 + (lane & 15);
        if (EPI == 0) {
          const float v = acc[mf][nf][r] + bias[gc];
          Hout[(size_t)gr * Nout + gc] = (_Float16)(g * fmaxf(v, 0.0f));
        } else {
          _Float16* P = (q ? p2 : p1) + (size_t)gr * Nout + gc;
          if (beta) *P = (_Float16)((float)*P + acc[mf][nf][r]);
          else      *P = (_Float16)acc[mf][nf][r];
        }
      }
    }
  }
}

// ---------------------------------------------------------------------------
extern "C" void kernel_launch(void* const* d_in, const int* in_sizes, int n_in,
                              void* d_out, int out_size, void* d_ws,
                              size_t ws_size, hipStream_t stream) {
  const float* x  = (const float*)d_in[0];
  const float* gw = (const float*)d_in[1];
  const float* gb = (const float*)d_in[2];
  const float* w1 = (const float*)d_in[3];
  const float* b1 = (const float*)d_in[4];
  const float* w2 = (const float*)d_in[5];
  const float* b2 = (const float*)d_in[6];
  float* out = (float*)d_out;

  const int N = 8192, D = 1024, H = 4096, E = 8;
  const size_t MB = 1ull << 20;

  char* ws = (char*)d_ws;
  float* gates  = (float*)ws;                    // 256 KB
  _Float16* x_h = (_Float16*)(ws + MB);          // 16 MB

  gates_kernel<<<N / 4, 256, 0, stream>>>(x, gw, gb, gates);
  cvt_f32_f16_kernel<<<(N * D / 8 + 255) / 256, 256, 0, stream>>>(x, x_h, N * D / 8);

  if (ws_size >= 346 * MB) {
    // ---- Tier A5: R18 structure + BATCHED w2t (R15 evidence: GEMM2 ran
    // 110us with batched w2t vs 130 with JIT — isolate that variable).
    // Single-expert GEMM1 -> HbufA/HbufB; GEMM2-pair dual-pointer K-halves;
    // pure-store pAll partials; combine8.
    _Float16* HbufA = (_Float16*)(ws + 17 * MB);   // 64 MB [N][H]
    _Float16* HbufB = (_Float16*)(ws + 81 * MB);   // 64 MB [N][H]
    _Float16* w1t   = (_Float16*)(ws + 145 * MB);  // 8 MB  [H][D] (JIT)
    _Float16* w2t   = (_Float16*)(ws + 153 * MB);  // 64 MB [E][D][H]
    _Float16* pAll  = (_Float16*)(ws + 217 * MB);  // 128 MB [8][N][D] (end 345)
    const size_t ND = (size_t)N * D;
    const size_t HD = (size_t)H * D;
    // all w2 transposes up-front: [E][H][D] -> [E][D][H]
    transpose_cvt_kernel<<<dim3(D / 32, H / 32, E), 256, 0, stream>>>(
        w2, w2t, H, D);
    for (int p = 0; p < 4; ++p) {
      // expert 2p -> HbufA
      transpose_cvt_kernel<<<dim3(H / 32, D / 32, 1), 256, 0, stream>>>(
          w1 + (size_t)(2 * p) * HD, w1t, D, H);
      gemm256_kernel<0><<<dim3(N / 256, H / 256), 512, 0, stream>>>(
          x_h, w1t, nullptr, nullptr, b1 + (size_t)(2 * p) * H, gates,
          2 * p, HbufA, nullptr, nullptr, 0, 0, D, D, D, H);
      // expert 2p+1 -> HbufB
      transpose_cvt_kernel<<<dim3(H / 32, D / 32, 1), 256, 0, stream>>>(
          w1 + (size_t)(2 * p + 1) * HD, w1t, D, H);
      gemm256_kernel<0><<<dim3(N / 256, H / 256), 512, 0, stream>>>(
          x_h, w1t, nullptr, nullptr, b1 + (size_t)(2 * p + 1) * H, gates,
          2 * p + 1, HbufB, nullptr, nullptr, 0, 0, D, D, D, H);
      // GEMM2 pair: q=0 {HbufA, w2t[2p]}, q=1 {HbufB, w2t[2p+1]}; pure store
      gemm256_kernel<1><<<dim3(N / 256, 8), 512, 0, stream>>>(
          HbufA, w2t + (size_t)(2 * p) * HD, HbufB,
          w2t + (size_t)(2 * p + 1) * HD, nullptr, nullptr, 0, nullptr,
          pAll + (size_t)(2 * p) * ND, pAll + (size_t)(2 * p + 1) * ND, 0, 0,
          H, H, H, D);
    }
    combine8_kernel<<<N * D / 8 / 256, 256, 0, stream>>>(gates, b2, pAll, out);
  } else if (ws_size >= 210 * MB) {
    // ---- Tier B: round-14 pairs (proven 1255us)
    _Float16* Hbuf2 = (_Float16*)(ws + 17 * MB);   // 128 MB [N][2H]
    _Float16* w2tp  = (_Float16*)(ws + 145 * MB);  // 16 MB  [D][2H]
    _Float16* w1tp  = (_Float16*)(ws + 161 * MB);  // 16 MB  [2H][D]
    _Float16* p1    = (_Float16*)(ws + 177 * MB);  // 16 MB  [N][D]
    _Float16* p2    = (_Float16*)(ws + 193 * MB);  // 16 MB  (end 209)
    for (int p = 0; p < 4; ++p) {
      transpose_cvt_kernel<<<dim3(H / 32, D / 32, 2), 256, 0, stream>>>(
          w1 + (size_t)(2 * p) * D * H, w1tp, D, H);
      transpose_cvt_kernel<<<dim3(D / 32, 2 * H / 32, 1), 256, 0, stream>>>(
          w2 + (size_t)(2 * p) * H * D, w2tp, 2 * H, D);
      gemm256_kernel<0><<<dim3(N / 256, 2 * H / 256), 512, 0, stream>>>(
          x_h, w1tp, nullptr, nullptr, b1 + (size_t)(2 * p) * H, gates,
          2 * p, Hbuf2, nullptr, nullptr, 0, 0, D, D, D, 2 * H);
      gemm256_kernel<1><<<dim3(N / 256, 8), 512, 0, stream>>>(
          Hbuf2, w2tp, Hbuf2, w2tp, nullptr, nullptr, 0, nullptr, p1, p2,
          p > 0, H, 2 * H, 2 * H, H, D);
    }
    combine_kernel<<<N * D / 8 / 256, 256, 0, stream>>>(gates, b2, p1, p2, out);
  } else if (ws_size >= 186 * MB) {
    // ---- Tier C: round-9 per-expert path + fp16 partials
    _Float16* Hbuf = (_Float16*)(ws + 17 * MB);    // 64 MB [N][H]
    _Float16* w2t  = (_Float16*)(ws + 81 * MB);    // 64 MB [E][D][H]
    _Float16* w1t  = (_Float16*)(ws + 145 * MB);   // 8 MB  [H][D]
    _Float16* p1   = (_Float16*)(ws + 153 * MB);   // 16 MB [N][D]
    _Float16* p2   = (_Float16*)(ws + 169 * MB);   // 16 MB (end 185)
    transpose_cvt_kernel<<<dim3(D / 32, H / 32, E), 256, 0, stream>>>(
        w2, w2t, H, D);
    for (int e = 0; e < E; ++e) {
      transpose_cvt_kernel<<<dim3(H / 32, D / 32, 1), 256, 0, stream>>>(
          w1 + (size_t)e * D * H, w1t, D, H);
      gemm256_kernel<0><<<dim3(N / 256, H / 256), 512, 0, stream>>>(
          x_h, w1t, nullptr, nullptr, b1 + (size_t)e * H, gates, e, Hbuf,
          nullptr, nullptr, 0, 0, D, D, D, H);
      gemm256_kernel<1><<<dim3(N / 256, 8), 512, 0, stream>>>(
          Hbuf, w2t + (size_t)e * D * H, Hbuf, w2t + (size_t)e * D * H,
          nullptr, nullptr, 0, nullptr, p1, p2, e > 0, H / 2, H, H, H / 2, D);
    }
    combine_kernel<<<N * D / 8 / 256, 256, 0, stream>>>(gates, b2, p1, p2, out);
  } else {
    // ---- Tier D: small ws (129 MB)
    _Float16* w1t  = (_Float16*)(ws + 17 * MB);    // 8 MB [H][D]
    _Float16* w2t  = (_Float16*)(ws + 25 * MB);    // 8 MB [D][H]
    _Float16* Hbuf = (_Float16*)(ws + 33 * MB);    // 64 MB [N][H]
    _Float16* p1   = (_Float16*)(ws + 97 * MB);    // 16 MB
    _Float16* p2   = (_Float16*)(ws + 113 * MB);   // 16 MB (end 129)
    for (int e = 0; e < E; ++e) {
      transpose_cvt_kernel<<<dim3(H / 32, D / 32, 1), 256, 0, stream>>>(
          w1 + (size_t)e * D * H, w1t, D, H);
      transpose_cvt_kernel<<<dim3(D / 32, H / 32, 1), 256, 0, stream>>>(
          w2 + (size_t)e * H * D, w2t, H, D);
      gemm256_kernel<0><<<dim3(N / 256, H / 256), 512, 0, stream>>>(
          x_h, w1t, nullptr, nullptr, b1 + (size_t)e * H, gates, e, Hbuf,
          nullptr, nullptr, 0, 0, D, D, D, H);
      gemm256_kernel<1><<<dim3(N / 256, 8), 512, 0, stream>>>(
          Hbuf, w2t, Hbuf, w2t, nullptr, nullptr, 0, nullptr, p1, p2, e > 0,
          H / 2, H, H, H / 2, D);
    }
    combine_kernel<<<N * D / 8 / 256, 256, 0, stream>>>(gates, b2, p1, p2, out);
  }
}

// Round 20
// 1177.282 us; speedup vs baseline: 1.0159x; 1.0159x over previous
//
#include <hip/hip_runtime.h>
#include <hip/hip_bf16.h>

typedef _Float16 half8 __attribute__((ext_vector_type(8)));
typedef _Float16 half4v __attribute__((ext_vector_type(4)));
typedef float floatx4 __attribute__((ext_vector_type(4)));

// ---------------------------------------------------------------------------
__device__ inline void gload_lds16(const void* g, void* l) {
  __builtin_amdgcn_global_load_lds(
      (const __attribute__((address_space(1))) unsigned int*)g,
      (__attribute__((address_space(3))) unsigned int*)l, 16, 0, 0);
}
__device__ inline unsigned lds_off(const void* p) {
  return (unsigned)(uintptr_t)(const __attribute__((address_space(3))) char*)p;
}
__device__ inline half8 ds_read128(unsigned off) {
  half8 r;
  asm volatile("ds_read_b128 %0, %1" : "=v"(r) : "v"(off));
  return r;
}
#define BARB()   __builtin_amdgcn_s_barrier()
#define WAITL0() asm volatile("s_waitcnt lgkmcnt(0)")
#define WAITV(n) asm volatile("s_waitcnt vmcnt(" #n ")")
#define SCHED0() __builtin_amdgcn_sched_barrier(0)

// Panel-chunked n-fast XCD swizzle (round-8).  Identity if gridDim.y%8 != 0.
__device__ inline void xcd_chunk_decode(int* mb, int* nk) {
  if (gridDim.y & 7) { *mb = blockIdx.x; *nk = blockIdx.y; return; }
  const int gx = gridDim.x;
  const int nb = gx * gridDim.y;
  const int b = blockIdx.x + gx * blockIdx.y;
  const int s = (b & 7) * (nb >> 3) + (b >> 3);  // bijective
  const int PW = gx * 8;
  const int p = s / PW, r = s % PW;
  *mb = r >> 3;
  *nk = p * 8 + (r & 7);
}

// ---------------------------------------------------------------------------
__global__ __launch_bounds__(256) void gates_kernel(
    const float* __restrict__ x, const float* __restrict__ gw,
    const float* __restrict__ gb, float* __restrict__ gates) {
  const int lane = threadIdx.x & 63, wid = threadIdx.x >> 6;
  const int n = blockIdx.x * 4 + wid;
  const float* xr = x + (size_t)n * 1024;
  float xv[16];
#pragma unroll
  for (int i = 0; i < 16; ++i) xv[i] = xr[lane + i * 64];
  float logit[8];
#pragma unroll
  for (int e = 0; e < 8; ++e) {
    const float* wr = gw + (size_t)e * 1024;
    float p = 0.f;
#pragma unroll
    for (int i = 0; i < 16; ++i) p += xv[i] * wr[lane + i * 64];
#pragma unroll
    for (int off = 32; off > 0; off >>= 1) p += __shfl_xor(p, off);
    logit[e] = p + gb[e];
  }
  float mx = logit[0];
#pragma unroll
  for (int e = 1; e < 8; ++e) mx = fmaxf(mx, logit[e]);
  float s = 0.f;
#pragma unroll
  for (int e = 0; e < 8; ++e) { logit[e] = expf(logit[e] - mx); s += logit[e]; }
  if (lane < 8) gates[(size_t)n * 8 + lane] = logit[lane] / s;
}

// ---------------------------------------------------------------------------
// out = p1 + p2 + sum_e gates*b2  (2 partials; fallback tiers)
__global__ __launch_bounds__(256) void combine_kernel(
    const float* __restrict__ gates, const float* __restrict__ b2,
    const _Float16* __restrict__ p1, const _Float16* __restrict__ p2,
    float* __restrict__ out) {
  const int i = blockIdx.x * 256 + threadIdx.x;
  const int n = i >> 7;
  const int d0 = (i & 127) << 3;
  const half8 a = *(const half8*)(p1 + ((size_t)n * 1024 + d0));
  const half8 b = *(const half8*)(p2 + ((size_t)n * 1024 + d0));
  float s[8];
#pragma unroll
  for (int j = 0; j < 8; ++j) s[j] = (float)a[j] + (float)b[j];
  const float* g = gates + (size_t)n * 8;
#pragma unroll
  for (int e = 0; e < 8; ++e) {
    const float ge = g[e];
    const float4* bb = (const float4*)(b2 + (size_t)e * 1024 + d0);
    const float4 b0 = bb[0], b1v = bb[1];
    s[0] += ge * b0.x; s[1] += ge * b0.y; s[2] += ge * b0.z; s[3] += ge * b0.w;
    s[4] += ge * b1v.x; s[5] += ge * b1v.y; s[6] += ge * b1v.z; s[7] += ge * b1v.w;
  }
  float4* o = (float4*)(out + (size_t)n * 1024 + d0);
  o[0] = make_float4(s[0], s[1], s[2], s[3]);
  o[1] = make_float4(s[4], s[5], s[6], s[7]);
}

// ---------------------------------------------------------------------------
// out = sum_{i<8} pAll[i] + sum_e gates*b2  (8 fp16 partials, pure store)
__global__ __launch_bounds__(256) void combine8_kernel(
    const float* __restrict__ gates, const float* __restrict__ b2,
    const _Float16* __restrict__ pAll, float* __restrict__ out) {
  const int i = blockIdx.x * 256 + threadIdx.x;  // 8 elems/thread
  const int n = i >> 7;
  const int d0 = (i & 127) << 3;
  const size_t off = (size_t)n * 1024 + d0;
  const size_t stride = (size_t)8192 * 1024;  // N*D
  float s[8] = {0, 0, 0, 0, 0, 0, 0, 0};
#pragma unroll
  for (int pi = 0; pi < 8; ++pi) {
    const half8 a = *(const half8*)(pAll + pi * stride + off);
#pragma unroll
    for (int j = 0; j < 8; ++j) s[j] += (float)a[j];
  }
  const float* g = gates + (size_t)n * 8;
#pragma unroll
  for (int e = 0; e < 8; ++e) {
    const float ge = g[e];
    const float4* bb = (const float4*)(b2 + (size_t)e * 1024 + d0);
    const float4 b0 = bb[0], b1v = bb[1];
    s[0] += ge * b0.x; s[1] += ge * b0.y; s[2] += ge * b0.z; s[3] += ge * b0.w;
    s[4] += ge * b1v.x; s[5] += ge * b1v.y; s[6] += ge * b1v.z; s[7] += ge * b1v.w;
  }
  float4* o = (float4*)(out + (size_t)n * 1024 + d0);
  o[0] = make_float4(s[0], s[1], s[2], s[3]);
  o[1] = make_float4(s[4], s[5], s[6], s[7]);
}

// ---------------------------------------------------------------------------
__global__ __launch_bounds__(256) void cvt_f32_f16_kernel(
    const float* __restrict__ in, _Float16* __restrict__ out, int n8) {
  const int i = blockIdx.x * 256 + threadIdx.x;
  if (i >= n8) return;
  const float4* p = (const float4*)(in + (size_t)i * 8);
  float4 a = p[0], b = p[1];
  half8 h;
  h[0] = (_Float16)a.x; h[1] = (_Float16)a.y; h[2] = (_Float16)a.z; h[3] = (_Float16)a.w;
  h[4] = (_Float16)b.x; h[5] = (_Float16)b.y; h[6] = (_Float16)b.z; h[7] = (_Float16)b.w;
  *(half8*)(out + (size_t)i * 8) = h;
}

// ---------------------------------------------------------------------------
// Vectorized transpose+cvt (verified r12/r14): out[z][c][r] = (fp16)
// in[z][r][c].  GRID CONTRACT: dim3(C/32, R/32, z).
__global__ __launch_bounds__(256) void transpose_cvt_kernel(
    const float* __restrict__ in, _Float16* __restrict__ out, int R, int C) {
  __shared__ _Float16 tile[32][36];
  const float* src = in + (size_t)blockIdx.z * R * C;
  _Float16* dst = out + (size_t)blockIdx.z * R * C;
  const int c0 = blockIdx.x << 5, r0 = blockIdx.y << 5;
  const int lr = threadIdx.x >> 3, lc = (threadIdx.x & 7) << 2;
  const float4 v = *(const float4*)&src[(size_t)(r0 + lr) * C + c0 + lc];
  half4v h;
  h[0] = (_Float16)v.x; h[1] = (_Float16)v.y;
  h[2] = (_Float16)v.z; h[3] = (_Float16)v.w;
  *(half4v*)&tile[lr][lc] = h;
  __syncthreads();
  const int oc = threadIdx.x >> 3, orr = (threadIdx.x & 7) << 2;
  half4v o;
#pragma unroll
  for (int i = 0; i < 4; ++i) o[i] = tile[orr + i][oc];
  *(half4v*)&dst[(size_t)(c0 + oc) * R + r0 + orr] = o;
}

// ---------------------------------------------------------------------------
// 256x256-tile, BK=64, 8-phase pipelined f16 MFMA GEMM — EXACT round-9
// staging schedule (best measured).
// EPI 0: Hout[gr*Nout + gc] = gate[gr][ebase + (n0>>12)] * relu(acc+bias[gc]).
// EPI 1: q = nk>>2 in {0,1}: K-window q*kOff, dest q? p2 : p1 (fp16,
//   exclusive owner per element); beta ? RMW : store.
template <int EPI>
__global__ __launch_bounds__(512, 2) void gemm256_kernel(
    const _Float16* __restrict__ A, const _Float16* __restrict__ Bt,
    const float* __restrict__ bias, const float* __restrict__ gates,
    int ebase, _Float16* __restrict__ Hout, _Float16* __restrict__ p1,
    _Float16* __restrict__ p2, int beta, int kOff, int lda, int ldb,
    int kLen, int Nout) {
  __shared__ _Float16 smem[2][4][8192];  // [buf][A0,A1,B0,B1][16KB]
  const int tid = threadIdx.x, lane = tid & 63, wid = tid >> 6;
  const int wm = wid >> 2, wn = wid & 3;

  int mb, nk;
  xcd_chunk_decode(&mb, &nk);
  const int m0 = mb * 256;
  int n0, kb = 0, q = 0;
  if (EPI == 1) { q = nk >> 2; n0 = (nk & 3) * 256; kb = q * kOff; }
  else          { n0 = nk * 256; }
  const int eg = (EPI == 0) ? ebase + (n0 >> 12) : 0;
  const int NT = kLen >> 6;

  floatx4 acc[8][4] = {};

  auto stage_half = [&](int h) {
    if (h >= 4 * NT) return;
    const int th = h >> 2, j = h & 3, bf = th & 1;
    const int k0 = kb + th * 64;
    const char* gb; int ld, rorig;
    if (j < 2) { gb = (const char*)A;  ld = lda; rorig = m0 + j * 128; }
    else       { gb = (const char*)Bt; ld = ldb; rorig = n0 + (j - 2) * 128; }
    _Float16* lb = &smem[bf][j][0];
#pragma unroll
    for (int i = 0; i < 2; ++i) {
      const int row = (wid * 2 + i) * 8 + (lane >> 3);
      const int gkb = ((lane & 7) * 16) ^ ((row & 7) << 4);  // inverse swizzle
      gload_lds16(gb + ((size_t)(rorig + row) * ld + k0) * 2 + gkb,
                  lb + (wid * 2 + i) * 512 + lane * 8);
    }
  };

  const unsigned smem0 = lds_off(&smem[0][0][0]);
  auto ldA = [&](int bf, int mf, int ks) -> half8 {
    const int row = mf * 16 + (lane & 15);
    const int col = (ks * 64 + ((lane >> 4) << 4)) ^ ((row & 7) << 4);
    return ds_read128(smem0 + (bf * 4 + wm) * 16384 + row * 128 + col);
  };
  auto ldB = [&](int bf, int nf, int ks) -> half8 {
    const int c = wn * 64 + nf * 16 + (lane & 15);
    const int r = c & 127;
    const int col = (ks * 64 + ((lane >> 4) << 4)) ^ ((r & 7) << 4);
    return ds_read128(smem0 + (bf * 4 + 2 + (c >> 7)) * 16384 + r * 128 + col);
  };

  stage_half(0); stage_half(1); stage_half(2); stage_half(3);
  stage_half(4 * 1 + 2); stage_half(4 * 1 + 3);
  WAITV(4); SCHED0();
  BARB();

#pragma unroll 1
  for (int t = 0; t < NT; ++t) {
    const int bf = t & 1;
    half8 a[4][2], bh[2][2], bl[2][2];
    // ---- P1
#pragma unroll
    for (int ks = 0; ks < 2; ++ks) {
#pragma unroll
      for (int m = 0; m < 4; ++m) a[m][ks] = ldA(bf, m, ks);
#pragma unroll
      for (int n = 0; n < 2; ++n) bh[n][ks] = ldB(bf, 2 + n, ks);
    }
    stage_half(4 * (t + 1) + 0);
    BARB(); WAITL0(); SCHED0();
    __builtin_amdgcn_s_setprio(1);
#pragma unroll
    for (int m = 0; m < 4; ++m)
#pragma unroll
      for (int n = 0; n < 2; ++n)
#pragma unroll
        for (int ks = 0; ks < 2; ++ks)
          acc[m][2 + n] = __builtin_amdgcn_mfma_f32_16x16x32_f16(
              a[m][ks], bh[n][ks], acc[m][2 + n], 0, 0, 0);
    __builtin_amdgcn_s_setprio(0);
    BARB();
    // ---- P2
#pragma unroll
    for (int ks = 0; ks < 2; ++ks)
#pragma unroll
      for (int n = 0; n < 2; ++n) bl[n][ks] = ldB(bf, n, ks);
    stage_half(4 * (t + 1) + 1);
    BARB(); WAITL0(); SCHED0();
    __builtin_amdgcn_s_setprio(1);
#pragma unroll
    for (int m = 0; m < 4; ++m)
#pragma unroll
      for (int n = 0; n < 2; ++n)
#pragma unroll
        for (int ks = 0; ks < 2; ++ks)
          acc[m][n] = __builtin_amdgcn_mfma_f32_16x16x32_f16(
              a[m][ks], bl[n][ks], acc[m][n], 0, 0, 0);
    __builtin_amdgcn_s_setprio(0);
    BARB();
    // ---- P3
#pragma unroll
    for (int ks = 0; ks < 2; ++ks)
#pragma unroll
      for (int m = 0; m < 4; ++m) a[m][ks] = ldA(bf, 4 + m, ks);
    stage_half(4 * (t + 2) + 2);
    BARB(); WAITL0(); SCHED0();
    __builtin_amdgcn_s_setprio(1);
#pragma unroll
    for (int m = 0; m < 4; ++m)
#pragma unroll
      for (int n = 0; n < 2; ++n)
#pragma unroll
        for (int ks = 0; ks < 2; ++ks)
          acc[4 + m][2 + n] = __builtin_amdgcn_mfma_f32_16x16x32_f16(
              a[m][ks], bh[n][ks], acc[4 + m][2 + n], 0, 0, 0);
    __builtin_amdgcn_s_setprio(0);
    BARB();
    // ---- P4
    stage_half(4 * (t + 2) + 3);
    BARB();
    __builtin_amdgcn_s_setprio(1);
#pragma unroll
    for (int m = 0; m < 4; ++m)
#pragma unroll
      for (int n = 0; n < 2; ++n)
#pragma unroll
        for (int ks = 0; ks < 2; ++ks)
          acc[4 + m][n] = __builtin_amdgcn_mfma_f32_16x16x32_f16(
              a[m][ks], bl[n][ks], acc[4 + m][n], 0, 0, 0);
    __builtin_amdgcn_s_setprio(0);
    if (t + 2 < NT) { WAITV(4); } else { WAITV(0); }
    SCHED0();
    BARB();
  }

  // epilogue: D-frag col = lane&15, row = (lane>>4)*4 + r
#pragma unroll
  for (int mf = 0; mf < 8; ++mf) {
    const int gr0 = m0 + wm * 128 + mf * 16 + ((lane >> 4) << 2);
#pragma unroll
    for (int r = 0; r < 4; ++r) {
      const int gr = gr0 + r;
      float g = 0.f;
      if (EPI == 0) g = gates[(size_t)gr * 8 + eg];
#pragma unroll
      for (int nf = 0; nf < 4; ++nf) {
        const int gc = n0 + wn * 64 + nf * 16 + (lane & 15);
        if (EPI == 0) {
          const float v = acc[mf][nf][r] + bias[gc];
          Hout[(size_t)gr * Nout + gc] = (_Float16)(g * fmaxf(v, 0.0f));
        } else {
          _Float16* P = (q ? p2 : p1) + (size_t)gr * Nout + gc;
          if (beta) *P = (_Float16)((float)*P + acc[mf][nf][r]);
          else      *P = (_Float16)acc[mf][nf][r];
        }
      }
    }
  }
}

// ---------------------------------------------------------------------------
extern "C" void kernel_launch(void* const* d_in, const int* in_sizes, int n_in,
                              void* d_out, int out_size, void* d_ws,
                              size_t ws_size, hipStream_t stream) {
  const float* x  = (const float*)d_in[0];
  const float* gw = (const float*)d_in[1];
  const float* gb = (const float*)d_in[2];
  const float* w1 = (const float*)d_in[3];
  const float* b1 = (const float*)d_in[4];
  const float* w2 = (const float*)d_in[5];
  const float* b2 = (const float*)d_in[6];
  float* out = (float*)d_out;

  const int N = 8192, D = 1024, H = 4096, E = 8;
  const size_t MB = 1ull << 20;

  char* ws = (char*)d_ws;
  float* gates  = (float*)ws;                    // 256 KB
  _Float16* x_h = (_Float16*)(ws + MB);          // 16 MB

  gates_kernel<<<N / 4, 256, 0, stream>>>(x, gw, gb, gates);
  cvt_f32_f16_kernel<<<(N * D / 8 + 255) / 256, 256, 0, stream>>>(x, x_h, N * D / 8);

  if (ws_size >= 306 * MB) {
    // ---- Tier A'' (round-16, measured best 1180.8us): expert pairs with
    // per-pair JIT transposes + 8 independent no-RMW fp16 partials.
    _Float16* Hbuf2 = (_Float16*)(ws + 17 * MB);   // 128 MB [N][2H]
    _Float16* w1tp  = (_Float16*)(ws + 145 * MB);  // 16 MB  [2H][D]
    _Float16* w2tp  = (_Float16*)(ws + 161 * MB);  // 16 MB  [D][2H]
    _Float16* pAll  = (_Float16*)(ws + 177 * MB);  // 128 MB [8][N][D] (end 305)
    const size_t ND = (size_t)N * D;
    for (int p = 0; p < 4; ++p) {
      transpose_cvt_kernel<<<dim3(H / 32, D / 32, 2), 256, 0, stream>>>(
          w1 + (size_t)(2 * p) * D * H, w1tp, D, H);
      transpose_cvt_kernel<<<dim3(D / 32, 2 * H / 32, 1), 256, 0, stream>>>(
          w2 + (size_t)(2 * p) * H * D, w2tp, 2 * H, D);
      gemm256_kernel<0><<<dim3(N / 256, 2 * H / 256), 512, 0, stream>>>(
          x_h, w1tp, b1 + (size_t)(2 * p) * H, gates, 2 * p, Hbuf2,
          nullptr, nullptr, 0, 0, D, D, D, 2 * H);
      gemm256_kernel<1><<<dim3(N / 256, 8), 512, 0, stream>>>(
          Hbuf2, w2tp, nullptr, nullptr, 0, nullptr,
          pAll + (size_t)(2 * p) * ND, pAll + (size_t)(2 * p + 1) * ND, 0, H,
          2 * H, 2 * H, H, D);
    }
    combine8_kernel<<<N * D / 8 / 256, 256, 0, stream>>>(gates, b2, pAll, out);
  } else if (ws_size >= 210 * MB) {
    // ---- Tier B: round-14 pairs (proven 1255us)
    _Float16* Hbuf2 = (_Float16*)(ws + 17 * MB);   // 128 MB [N][2H]
    _Float16* w2tp  = (_Float16*)(ws + 145 * MB);  // 16 MB  [D][2H]
    _Float16* w1tp  = (_Float16*)(ws + 161 * MB);  // 16 MB  [2H][D]
    _Float16* p1    = (_Float16*)(ws + 177 * MB);  // 16 MB  [N][D]
    _Float16* p2    = (_Float16*)(ws + 193 * MB);  // 16 MB  (end 209)
    for (int p = 0; p < 4; ++p) {
      transpose_cvt_kernel<<<dim3(H / 32, D / 32, 2), 256, 0, stream>>>(
          w1 + (size_t)(2 * p) * D * H, w1tp, D, H);
      transpose_cvt_kernel<<<dim3(D / 32, 2 * H / 32, 1), 256, 0, stream>>>(
          w2 + (size_t)(2 * p) * H * D, w2tp, 2 * H, D);
      gemm256_kernel<0><<<dim3(N / 256, 2 * H / 256), 512, 0, stream>>>(
          x_h, w1tp, b1 + (size_t)(2 * p) * H, gates, 2 * p, Hbuf2,
          nullptr, nullptr, 0, 0, D, D, D, 2 * H);
      gemm256_kernel<1><<<dim3(N / 256, 8), 512, 0, stream>>>(
          Hbuf2, w2tp, nullptr, nullptr, 0, nullptr, p1, p2, p > 0, H,
          2 * H, 2 * H, H, D);
    }
    combine_kernel<<<N * D / 8 / 256, 256, 0, stream>>>(gates, b2, p1, p2, out);
  } else if (ws_size >= 186 * MB) {
    // ---- Tier C: round-9 per-expert path + fp16 partials
    _Float16* Hbuf = (_Float16*)(ws + 17 * MB);    // 64 MB [N][H]
    _Float16* w2t  = (_Float16*)(ws + 81 * MB);    // 64 MB [E][D][H]
    _Float16* w1t  = (_Float16*)(ws + 145 * MB);   // 8 MB  [H][D]
    _Float16* p1   = (_Float16*)(ws + 153 * MB);   // 16 MB [N][D]
    _Float16* p2   = (_Float16*)(ws + 169 * MB);   // 16 MB (end 185)
    transpose_cvt_kernel<<<dim3(D / 32, H / 32, E), 256, 0, stream>>>(
        w2, w2t, H, D);
    for (int e = 0; e < E; ++e) {
      transpose_cvt_kernel<<<dim3(H / 32, D / 32, 1), 256, 0, stream>>>(
          w1 + (size_t)e * D * H, w1t, D, H);
      gemm256_kernel<0><<<dim3(N / 256, H / 256), 512, 0, stream>>>(
          x_h, w1t, b1 + (size_t)e * H, gates, e, Hbuf, nullptr, nullptr, 0,
          0, D, D, D, H);
      gemm256_kernel<1><<<dim3(N / 256, 8), 512, 0, stream>>>(
          Hbuf, w2t + (size_t)e * D * H, nullptr, nullptr, 0, nullptr,
          p1, p2, e > 0, H / 2, H, H, H / 2, D);
    }
    combine_kernel<<<N * D / 8 / 256, 256, 0, stream>>>(gates, b2, p1, p2, out);
  } else {
    // ---- Tier D: small ws (129 MB)
    _Float16* w1t  = (_Float16*)(ws + 17 * MB);    // 8 MB [H][D]
    _Float16* w2t  = (_Float16*)(ws + 25 * MB);    // 8 MB [D][H]
    _Float16* Hbuf = (_Float16*)(ws + 33 * MB);    // 64 MB [N][H]
    _Float16* p1   = (_Float16*)(ws + 97 * MB);    // 16 MB
    _Float16* p2   = (_Float16*)(ws + 113 * MB);   // 16 MB (end 129)
    for (int e = 0; e < E; ++e) {
      transpose_cvt_kernel<<<dim3(H / 32, D / 32, 1), 256, 0, stream>>>(
          w1 + (size_t)e * D * H, w1t, D, H);
      transpose_cvt_kernel<<<dim3(D / 32, H / 32, 1), 256, 0, stream>>>(
          w2 + (size_t)e * H * D, w2t, H, D);
      gemm256_kernel<0><<<dim3(N / 256, H / 256), 512, 0, stream>>>(
          x_h, w1t, b1 + (size_t)e * H, gates, e, Hbuf, nullptr, nullptr, 0,
          0, D, D, D, H);
      gemm256_kernel<1><<<dim3(N / 256, 8), 512, 0, stream>>>(
          Hbuf, w2t, nullptr, nullptr, 0, nullptr, p1, p2, e > 0, H / 2,
          H, H, H / 2, D);
    }
    combine_kernel<<<N * D / 8 / 256, 256, 0, stream>>>(gates, b2, p1, p2, out);
  }
}